// Round 18
// baseline (162.836 us; speedup 1.0000x reference)
//
#include <hip/hip_runtime.h>

typedef __bf16 bf16x8 __attribute__((ext_vector_type(8)));
typedef float f32x4 __attribute__((ext_vector_type(4)));
typedef float f32x16 __attribute__((ext_vector_type(16)));
typedef unsigned short u16;

__device__ inline u16 f2bf(float f) {
  union { float f; unsigned int u; } v; v.f = f;
  unsigned int r = v.u + 0x7fffu + ((v.u >> 16) & 1u);
  return (u16)(r >> 16);
}

__device__ inline void load_lds16(const void* g, void* l) {
  __builtin_amdgcn_global_load_lds((const __attribute__((address_space(1))) unsigned int*)g,
                                   (__attribute__((address_space(3))) unsigned int*)l, 16, 0, 0);
}

// ---------------- merged prepass: x->bf16, w_attn^T->bf16, w_proj^T->bf16 ----------------
__global__ __launch_bounds__(256) void prep(const float* __restrict__ x,
                                            const float* __restrict__ w_attn,
                                            const float* __restrict__ w_proj,
                                            u16* __restrict__ xb, u16* __restrict__ wTa,
                                            u16* __restrict__ wTp) {
  const int b = blockIdx.x;
  const int tid = threadIdx.x;
  if (b < 3072) {
    const int i = b * 1024 + tid * 4;
    float4 v = *(const float4*)(x + i);
    ushort4 o;
    o.x = f2bf(v.x); o.y = f2bf(v.y); o.z = f2bf(v.z); o.w = f2bf(v.w);
    *(ushort4*)(xb + i) = o;
    return;
  }
  __shared__ float tile[32][33];
  const float* in;
  u16* out;
  int R, C, c0, r0;
  if (b < 4800) {
    const int b2 = b - 3072;
    in = w_attn; out = wTa; R = 768; C = 2304;
    c0 = (b2 % 72) * 32; r0 = (b2 / 72) * 32;
  } else {
    const int b3 = b - 4800;
    in = w_proj; out = wTp; R = 768; C = 768;
    c0 = (b3 % 24) * 32; r0 = (b3 / 24) * 32;
  }
  const int tx = tid & 31, ty = tid >> 5;
#pragma unroll
  for (int i = ty; i < 32; i += 8)
    tile[i][tx] = in[(size_t)(r0 + i) * C + c0 + tx];
  __syncthreads();
#pragma unroll
  for (int i = ty; i < 32; i += 8)
    out[(size_t)(c0 + i) * R + r0 + tx] = f2bf(tile[tx][i]);
}

// V transpose: vT[h][d][s] from qkv[s][1536 + h*64 + d]
__global__ __launch_bounds__(256) void vtrans(const u16* __restrict__ qkv, u16* __restrict__ vT) {
  const int h = blockIdx.y;
  const int s0 = blockIdx.x * 64;
  const int tid = threadIdx.x;
  __shared__ u16 T[64][72];
  {
    const int key = tid >> 2, dq = (tid & 3) * 16;
    const u16* g = qkv + (size_t)(s0 + key) * 2304 + 1536 + h * 64 + dq;
    *(uint4*)&T[key][dq] = *(const uint4*)g;
    *(uint4*)&T[key][dq + 8] = *(const uint4*)(g + 8);
  }
  __syncthreads();
  {
    const int d = tid >> 2, sq = (tid & 3) * 16;
    u16 tmp[16];
#pragma unroll
    for (int e = 0; e < 16; ++e) tmp[e] = T[sq + e][d];
    u16* o = vT + ((size_t)h * 64 + d) * 4096 + s0 + sq;
    *(uint4*)o = *(uint4*)tmp;
    *(uint4*)(o + 8) = *(uint4*)(tmp + 8);
  }
}

// ---------------- GEMM: C = A[M,K] * BT[N,K]^T + bias, bf16 in ----------------
template <int BF16_OUT>
__global__ __launch_bounds__(256) void gemm_bt(const u16* __restrict__ A, const u16* __restrict__ BT,
                                               const float* __restrict__ bias, void* __restrict__ Cv,
                                               int M, int N, int K, int nx) {
  __shared__ __align__(16) u16 As[128 * 32];
  __shared__ __align__(16) u16 Bs[128 * 32];
  const int tid = threadIdx.x;
  const int wave = tid >> 6, lane = tid & 63;
  const int g = lane >> 4, lr = lane & 15;
  const int bid = blockIdx.x;
  const int swz = (bid & 7) * ((int)gridDim.x >> 3) + (bid >> 3);
  const int m0 = (swz / nx) * 128, n0 = (swz % nx) * 128;
  const int wr = (wave >> 1) * 64, wc = (wave & 1) * 64;
  f32x4 acc[4][4] = {};

  for (int k0 = 0; k0 < K; k0 += 32) {
    __syncthreads();
#pragma unroll
    for (int j = 0; j < 2; ++j) {
      const int e = tid * 8 + j * 2048;
      const int r = e >> 5, c = e & 31;
      const u16* ga = A + (size_t)(m0 + r) * K + k0 + c;
      const u16* gb = BT + (size_t)(n0 + r) * K + k0 + c;
      load_lds16(ga, (void*)(As + wave * 512 + j * 2048));
      load_lds16(gb, (void*)(Bs + wave * 512 + j * 2048));
    }
    __syncthreads();
    const u16* pa = As + (wr + lr) * 32 + g * 8;
    const u16* pb = Bs + (wc + lr) * 32 + g * 8;
    bf16x8 a[4], b[4];
#pragma unroll
    for (int i = 0; i < 4; ++i) a[i] = *(const bf16x8*)(pa + i * 16 * 32);
#pragma unroll
    for (int j = 0; j < 4; ++j) b[j] = *(const bf16x8*)(pb + j * 16 * 32);
#pragma unroll
    for (int i = 0; i < 4; ++i)
#pragma unroll
      for (int j = 0; j < 4; ++j)
        acc[i][j] = __builtin_amdgcn_mfma_f32_16x16x32_bf16(a[i], b[j], acc[i][j], 0, 0, 0);
  }

#pragma unroll
  for (int i = 0; i < 4; ++i)
#pragma unroll
    for (int j = 0; j < 4; ++j)
#pragma unroll
      for (int r = 0; r < 4; ++r) {
        int row = m0 + wr + i * 16 + g * 4 + r;
        int col = n0 + wc + j * 16 + lr;
        float v = acc[i][j][r] + bias[col];
        if (BF16_OUT)
          ((u16*)Cv)[(size_t)row * N + col] = f2bf(v);
        else
          ((float*)Cv)[(size_t)row * N + col] = v;
      }
}

// ---------------- causal flash attention: 4 waves/block share staged K/V (R8 body) ----------------
// Softmax max/sum as NESTED EXPRESSION trees (depth ~5, no named arrays -> no spill).
// Units with g < 8 cover their full causal range -> normalized direct write (no combine).
#define MNEG 30000.0f
template <int CH, int DIRECT>
__global__ __launch_bounds__(256, 3) void attn(const u16* __restrict__ qkv, const u16* __restrict__ vT,
                                               u16* __restrict__ pO, float* __restrict__ pml,
                                               u16* __restrict__ aout) {
  __shared__ __align__(16) u16 KV[4][4096];  // K buf0,buf1, V buf0,buf1 (swizzled 64x64)

  const int bid = blockIdx.x;
  const int h = bid % 12;
  int g, c;
  if (DIRECT) {
    g = 31 - bid / 12;
    c = 0;
  } else {
    const int u = 79 - bid / 12;  // heavy chunks first
    if (u < 8) { g = u; c = 0; }
    else if (u < 24) { g = 8 + ((u - 8) >> 1); c = (u - 8) & 1; }
    else if (u < 48) { g = 16 + (u - 24) / 3; c = (u - 24) % 3; }
    else { g = 24 + ((u - 48) >> 2); c = (u - 48) & 3; }
  }

  const int tid = threadIdx.x;
  const int wave = tid >> 6;
  const int l = tid & 63;
  const int lr = l & 31;   // q-row within wave's tile
  const int H = l >> 5;    // lane half
  const int H4 = H * 4, H8 = H * 8;

  const int qt = 4 * g + wave;
  const int q0 = qt * 32;
  const int nkt = (qt >> 1) + 1;              // tiles this wave needs
  const int t0 = DIRECT ? 0 : c * CH;
  const int tend = min(2 * g + 2, t0 + CH);   // block-uniform tile range

  const u16* kgb = qkv + 768 + h * 64;
  const u16* vgb = vT + (size_t)h * 64 * 4096;

  // staging: wave w issue i covers rows 16w+8i..+7; lane -> row 16w+8i+srow, chunk l&7
  const int srow = l >> 3;
  int kSo[2], vSo[2];
#pragma unroll
  for (int i = 0; i < 2; ++i) {
    const int row = 16 * wave + 8 * i + srow;
    const int sc = ((l & 7) ^ srow ^ (2 * wave + i)) << 3;
    kSo[i] = row * 2304 + sc;
    vSo[i] = row * 4096 + sc;
  }

  // hoisted LDS read pointers (K buf0; V = +8192, buf1 = +4096)
  const u16* Rd[2][4];
#pragma unroll
  for (int b2 = 0; b2 < 2; ++b2) {
    const int row = 32 * b2 + lr;
    const int sw = (row ^ (row >> 3)) & 7;
#pragma unroll
    for (int cc = 0; cc < 4; ++cc)
      Rd[b2][cc] = &KV[0][row * 64 + (((2 * cc + H) ^ sw) << 3)];
  }

  // Q B-fragments, prescaled by 0.125*log2(e)
  bf16x8 qB[4];
  {
    const u16* qp = qkv + (size_t)(q0 + lr) * 2304 + h * 64;
    const float qs = 0.125f * 1.4426950408889634f;
#pragma unroll
    for (int cc = 0; cc < 4; ++cc) {
      bf16x8 raw = *(const bf16x8*)(qp + 16 * cc + H8);
#pragma unroll
      for (int e = 0; e < 8; ++e) qB[cc][e] = (__bf16)((float)raw[e] * qs);
    }
  }

  f32x16 O[2] = {};
  float mst = -MNEG, lst = 0.f;

#define STAGE(T, BUF)                                                      \
  {                                                                        \
    const size_t kk = (size_t)(T) * 64;                                    \
    _Pragma("unroll") for (int i = 0; i < 2; ++i) {                        \
      load_lds16(kgb + kk * 2304 + kSo[i], &KV[(BUF)][(2 * wave + i) * 512]); \
      load_lds16(vgb + kk + vSo[i], &KV[2 + (BUF)][(2 * wave + i) * 512]); \
    }                                                                      \
  }

#define BODY(T, BUF)                                                                        \
  {                                                                                         \
    if ((T) + 1 < tend) {                                                                   \
      STAGE((T) + 1, (BUF) ^ 1);                                                            \
      asm volatile("s_waitcnt vmcnt(4)" ::: "memory");                                      \
    } else {                                                                                \
      asm volatile("s_waitcnt vmcnt(0)" ::: "memory");                                      \
    }                                                                                       \
    __builtin_amdgcn_s_barrier();                                                           \
    __builtin_amdgcn_sched_barrier(0);                                                      \
    f32x16 s[2] = {};                                                                       \
    _Pragma("unroll") for (int kb = 0; kb < 2; ++kb)                                        \
      _Pragma("unroll") for (int cc = 0; cc < 4; ++cc) {                                    \
        bf16x8 kf = *(const bf16x8*)(Rd[kb][cc] + (BUF) * 4096);                            \
        s[kb] = __builtin_amdgcn_mfma_f32_32x32x16_bf16(kf, qB[cc], s[kb], 0, 0, 0);        \
      }                                                                                     \
    bf16x8 vf[2][4];                                                                        \
    _Pragma("unroll") for (int da = 0; da < 2; ++da)                                        \
      _Pragma("unroll") for (int cc = 0; cc < 4; ++cc)                                      \
        vf[da][cc] = *(const bf16x8*)(Rd[da][cc] + 8192 + (BUF) * 4096);                    \
    if ((T) >= nkt - 1) {                                                                   \
      const int rel = q0 + lr - (T) * 64;                                                   \
      _Pragma("unroll") for (int kb = 0; kb < 2; ++kb)                                      \
        _Pragma("unroll") for (int r = 0; r < 16; ++r)                                      \
          if (32 * kb + (r & 3) + 8 * (r >> 2) + H4 > rel) s[kb][r] = -MNEG;                \
    }                                                                                       \
    /* max as nested expression tree (depth 5, ~4 live temps) */                            \
    float mx = fmaxf(                                                                       \
        fmaxf(fmaxf(fmaxf(fmaxf(s[0][0], s[0][1]), fmaxf(s[0][2], s[0][3])),                \
                    fmaxf(fmaxf(s[0][4], s[0][5]), fmaxf(s[0][6], s[0][7]))),               \
              fmaxf(fmaxf(fmaxf(s[0][8], s[0][9]), fmaxf(s[0][10], s[0][11])),              \
                    fmaxf(fmaxf(s[0][12], s[0][13]), fmaxf(s[0][14], s[0][15])))),          \
        fmaxf(fmaxf(fmaxf(fmaxf(s[1][0], s[1][1]), fmaxf(s[1][2], s[1][3])),                \
                    fmaxf(fmaxf(s[1][4], s[1][5]), fmaxf(s[1][6], s[1][7]))),               \
              fmaxf(fmaxf(fmaxf(s[1][8], s[1][9]), fmaxf(s[1][10], s[1][11])),              \
                    fmaxf(fmaxf(s[1][12], s[1][13]), fmaxf(s[1][14], s[1][15])))));         \
    mx = fmaxf(mx, __shfl_xor(mx, 32));                                                     \
    if (__any(mx > mst + 12.f)) {                                                           \
      const float mn = fmaxf(mst, mx);                                                      \
      const float alpha = __builtin_amdgcn_exp2f(mst - mn);                                 \
      mst = mn;                                                                             \
      lst *= alpha;                                                                         \
      O[0] *= alpha;                                                                        \
      O[1] *= alpha;                                                                        \
    }                                                                                       \
    _Pragma("unroll") for (int kb = 0; kb < 2; ++kb)                                        \
      _Pragma("unroll") for (int r = 0; r < 16; ++r)                                        \
        s[kb][r] = __builtin_amdgcn_exp2f(s[kb][r] - mst);                                  \
    /* sum as nested expression tree */                                                     \
    float rs = ((((s[0][0] + s[0][1]) + (s[0][2] + s[0][3])) +                              \
                 ((s[0][4] + s[0][5]) + (s[0][6] + s[0][7]))) +                             \
                (((s[0][8] + s[0][9]) + (s[0][10] + s[0][11])) +                            \
                 ((s[0][12] + s[0][13]) + (s[0][14] + s[0][15])))) +                        \
               ((((s[1][0] + s[1][1]) + (s[1][2] + s[1][3])) +                              \
                 ((s[1][4] + s[1][5]) + (s[1][6] + s[1][7]))) +                             \
                (((s[1][8] + s[1][9]) + (s[1][10] + s[1][11])) +                            \
                 ((s[1][12] + s[1][13]) + (s[1][14] + s[1][15]))));                         \
    rs += __shfl_xor(rs, 32);                                                               \
    lst += rs;                                                                              \
    unsigned w[16];                                                                         \
    _Pragma("unroll") for (int kb = 0; kb < 2; ++kb)                                        \
      _Pragma("unroll") for (int j2 = 0; j2 < 4; ++j2) {                                    \
        asm("v_cvt_pk_bf16_f32 %0, %1, %2"                                                  \
            : "=v"(w[kb * 8 + j2 * 2]) : "v"(s[kb][4 * j2]), "v"(s[kb][4 * j2 + 1]));       \
        asm("v_cvt_pk_bf16_f32 %0, %1, %2"                                                  \
            : "=v"(w[kb * 8 + j2 * 2 + 1]) : "v"(s[kb][4 * j2 + 2]), "v"(s[kb][4 * j2 + 3])); \
      }                                                                                     \
    unsigned recv[8];                                                                       \
    _Pragma("unroll") for (int cc = 0; cc < 4; ++cc)                                        \
      _Pragma("unroll") for (int m = 0; m < 2; ++m) {                                       \
        const unsigned send = H ? w[4 * cc + m] : w[4 * cc + 2 + m];                        \
        recv[cc * 2 + m] = (unsigned)__shfl_xor((int)send, 32);                             \
      }                                                                                     \
    _Pragma("unroll") for (int cc = 0; cc < 4; ++cc) {                                      \
      union { unsigned u[4]; bf16x8 v; } Bp;                                                \
      Bp.u[0] = H ? recv[2 * cc] : w[4 * cc];                                               \
      Bp.u[1] = H ? recv[2 * cc + 1] : w[4 * cc + 1];                                       \
      Bp.u[2] = H ? w[4 * cc + 2] : recv[2 * cc];                                           \
      Bp.u[3] = H ? w[4 * cc + 3] : recv[2 * cc + 1];                                       \
      O[0] = __builtin_amdgcn_mfma_f32_32x32x16_bf16(vf[0][cc], Bp.v, O[0], 0, 0, 0);       \
      O[1] = __builtin_amdgcn_mfma_f32_32x32x16_bf16(vf[1][cc], Bp.v, O[1], 0, 0, 0);       \
    }                                                                                       \
    __builtin_amdgcn_s_barrier();                                                           \
  }

  STAGE(t0, 0);
  int t = t0;
  for (; t + 2 <= tend; t += 2) {
    BODY(t, 0);
    BODY(t + 1, 1);
  }
  if (t < tend) BODY(t, 0);
#undef BODY
#undef STAGE

  if (DIRECT || g < 8) {
    const float inv = 1.0f / lst;
    u16* orow = aout + (size_t)(q0 + lr) * 768 + h * 64;
#pragma unroll
    for (int da = 0; da < 2; ++da)
#pragma unroll
      for (int j2 = 0; j2 < 4; ++j2) {
        ushort4 st;
        st.x = f2bf(O[da][4 * j2 + 0] * inv);
        st.y = f2bf(O[da][4 * j2 + 1] * inv);
        st.z = f2bf(O[da][4 * j2 + 2] * inv);
        st.w = f2bf(O[da][4 * j2 + 3] * inv);
        *(ushort4*)(orow + 32 * da + 8 * j2 + H4) = st;
      }
  } else {
    const int slot = (h * 128 + qt) * 4 + c;
    u16* po = pO + (size_t)slot * 2048 + lr * 64;
#pragma unroll
    for (int da = 0; da < 2; ++da)
#pragma unroll
      for (int j2 = 0; j2 < 4; ++j2) {
        ushort4 st;
        st.x = f2bf(O[da][4 * j2 + 0]);
        st.y = f2bf(O[da][4 * j2 + 1]);
        st.z = f2bf(O[da][4 * j2 + 2]);
        st.w = f2bf(O[da][4 * j2 + 3]);
        *(ushort4*)(po + 32 * da + 8 * j2 + H4) = st;
      }
    if (H == 0) {
      float2 ml; ml.x = mst; ml.y = lst;
      *(float2*)(pml + (size_t)slot * 64 + lr * 2) = ml;
    }
  }
}

// combine partials: one block per (h, qt) with qt >= 32
__global__ __launch_bounds__(64) void combine(const u16* __restrict__ pO, const float* __restrict__ pml,
                                              u16* __restrict__ aout, int ncmax, int CHv) {
  const int bid = blockIdx.x;
  const int h = bid % 12, qt = 32 + bid / 12;
  const int nkt = (qt >> 1) + 1;
  const int nc = (nkt + CHv - 1) / CHv;
  const int sb = (h * 128 + qt) * ncmax;
  const int t = threadIdx.x;
  const int row = t & 31, H = t >> 5;

  float m[4], lw[4];
  float M = -__builtin_inff();
#pragma unroll
  for (int c = 0; c < 4; ++c)
    if (c < nc) {
      m[c] = pml[(size_t)(sb + c) * 64 + row * 2];
      M = fmaxf(M, m[c]);
    }
  float L = 0.f;
#pragma unroll
  for (int c = 0; c < 4; ++c)
    if (c < nc) {
      lw[c] = __builtin_amdgcn_exp2f(m[c] - M);
      L += pml[(size_t)(sb + c) * 64 + row * 2 + 1] * lw[c];
    }

  float acc[32] = {};
#pragma unroll
  for (int c = 0; c < 4; ++c)
    if (c < nc) {
      const u16* p = pO + (size_t)(sb + c) * 2048 + row * 64 + 32 * H;
      const float wgt = lw[c];
#pragma unroll
      for (int k = 0; k < 4; ++k) {
        bf16x8 v = *(const bf16x8*)(p + 8 * k);
#pragma unroll
        for (int e = 0; e < 8; ++e) acc[k * 8 + e] += (float)v[e] * wgt;
      }
    }

  const float inv = 1.0f / L;
  u16 ov[32];
#pragma unroll
  for (int d = 0; d < 32; ++d) ov[d] = f2bf(acc[d] * inv);
  u16* dst = aout + (size_t)(qt * 32 + row) * 768 + h * 64 + 32 * H;
#pragma unroll
  for (int k = 0; k < 4; ++k) *(uint4*)(dst + 8 * k) = *(const uint4*)(ov + 8 * k);
}

// ---------------- launch ----------------
extern "C" void kernel_launch(void* const* d_in, const int* in_sizes, int n_in,
                              void* d_out, int out_size, void* d_ws, size_t ws_size,
                              hipStream_t stream) {
  const float* x = (const float*)d_in[0];
  const float* w_attn = (const float*)d_in[1];
  const float* b_attn = (const float*)d_in[2];
  const float* w_proj = (const float*)d_in[3];
  const float* b_proj = (const float*)d_in[4];
  float* out = (float*)d_out;

  const int S = 4096, D = 768;
  u16* xb = (u16*)d_ws;                 // [4096][768]
  u16* wTa = xb + (size_t)S * D;        // [2304][768]
  u16* wTp = wTa + (size_t)3 * D * D;   // [768][768]
  u16* qkv = wTp + (size_t)D * D;       // [4096][2304]
  u16* abuf = qkv + (size_t)S * 3 * D;  // [4096][768]
  u16* vTb = abuf + (size_t)S * D;      // [12][64][4096]
  u16* pO = vTb + (size_t)12 * 64 * 4096;

  const size_t base_bytes = (size_t)(3145728 + 1769472 + 589824 + 9437184 + 3145728 + 3145728) * 2;
  const size_t need16 = base_bytes + (size_t)6144 * 2048 * 2 + (size_t)6144 * 64 * 4;

  prep<<<dim3(5376), 256, 0, stream>>>(x, w_attn, w_proj, xb, wTa, wTp);
  gemm_bt<1><<<dim3(576), 256, 0, stream>>>(xb, wTa, b_attn, qkv, S, 3 * D, D, 18);
  vtrans<<<dim3(S / 64, 12), 256, 0, stream>>>(qkv, vTb);

  if (ws_size >= need16) {
    float* pml = (float*)(pO + (size_t)6144 * 2048);
    attn<16, 0><<<dim3(12 * 80), 256, 0, stream>>>(qkv, vTb, pO, pml, abuf);
    combine<<<dim3(12 * 96), 64, 0, stream>>>(pO, pml, abuf, 4, 16);
  } else {
    attn<64, 1><<<dim3(12 * 32), 256, 0, stream>>>(qkv, vTb, abuf, (float*)abuf, abuf);
  }

  gemm_bt<0><<<dim3(192), 256, 0, stream>>>(abuf, wTp, b_proj, out, S, D, D, 6);
}

// Round 19
// 135.349 us; speedup vs baseline: 1.2031x; 1.2031x over previous
//
#include <hip/hip_runtime.h>

typedef __bf16 bf16x8 __attribute__((ext_vector_type(8)));
typedef float f32x4 __attribute__((ext_vector_type(4)));
typedef float f32x16 __attribute__((ext_vector_type(16)));
typedef unsigned short u16;

__device__ inline u16 f2bf(float f) {
  union { float f; unsigned int u; } v; v.f = f;
  unsigned int r = v.u + 0x7fffu + ((v.u >> 16) & 1u);
  return (u16)(r >> 16);
}

__device__ inline void load_lds16(const void* g, void* l) {
  __builtin_amdgcn_global_load_lds((const __attribute__((address_space(1))) unsigned int*)g,
                                   (__attribute__((address_space(3))) unsigned int*)l, 16, 0, 0);
}

// ---------------- merged prepass: x->bf16, w_attn^T->bf16, w_proj^T->bf16 ----------------
__global__ __launch_bounds__(256) void prep(const float* __restrict__ x,
                                            const float* __restrict__ w_attn,
                                            const float* __restrict__ w_proj,
                                            u16* __restrict__ xb, u16* __restrict__ wTa,
                                            u16* __restrict__ wTp) {
  const int b = blockIdx.x;
  const int tid = threadIdx.x;
  if (b < 3072) {
    const int i = b * 1024 + tid * 4;
    float4 v = *(const float4*)(x + i);
    ushort4 o;
    o.x = f2bf(v.x); o.y = f2bf(v.y); o.z = f2bf(v.z); o.w = f2bf(v.w);
    *(ushort4*)(xb + i) = o;
    return;
  }
  __shared__ float tile[32][33];
  const float* in;
  u16* out;
  int R, C, c0, r0;
  if (b < 4800) {
    const int b2 = b - 3072;
    in = w_attn; out = wTa; R = 768; C = 2304;
    c0 = (b2 % 72) * 32; r0 = (b2 / 72) * 32;
  } else {
    const int b3 = b - 4800;
    in = w_proj; out = wTp; R = 768; C = 768;
    c0 = (b3 % 24) * 32; r0 = (b3 / 24) * 32;
  }
  const int tx = tid & 31, ty = tid >> 5;
#pragma unroll
  for (int i = ty; i < 32; i += 8)
    tile[i][tx] = in[(size_t)(r0 + i) * C + c0 + tx];
  __syncthreads();
#pragma unroll
  for (int i = ty; i < 32; i += 8)
    out[(size_t)(c0 + i) * R + r0 + tx] = f2bf(tile[tx][i]);
}

// V transpose: vT[h][d][s] from qkv[s][1536 + h*64 + d]
__global__ __launch_bounds__(256) void vtrans(const u16* __restrict__ qkv, u16* __restrict__ vT) {
  const int h = blockIdx.y;
  const int s0 = blockIdx.x * 64;
  const int tid = threadIdx.x;
  __shared__ u16 T[64][72];
  {
    const int key = tid >> 2, dq = (tid & 3) * 16;
    const u16* g = qkv + (size_t)(s0 + key) * 2304 + 1536 + h * 64 + dq;
    *(uint4*)&T[key][dq] = *(const uint4*)g;
    *(uint4*)&T[key][dq + 8] = *(const uint4*)(g + 8);
  }
  __syncthreads();
  {
    const int d = tid >> 2, sq = (tid & 3) * 16;
    u16 tmp[16];
#pragma unroll
    for (int e = 0; e < 16; ++e) tmp[e] = T[sq + e][d];
    u16* o = vT + ((size_t)h * 64 + d) * 4096 + s0 + sq;
    *(uint4*)o = *(uint4*)tmp;
    *(uint4*)(o + 8) = *(uint4*)(tmp + 8);
  }
}

// ---------------- GEMM: C = A[M,K] * BT[N,K]^T + bias, bf16 in ----------------
template <int BF16_OUT>
__global__ __launch_bounds__(256) void gemm_bt(const u16* __restrict__ A, const u16* __restrict__ BT,
                                               const float* __restrict__ bias, void* __restrict__ Cv,
                                               int M, int N, int K, int nx) {
  __shared__ __align__(16) u16 As[128 * 32];
  __shared__ __align__(16) u16 Bs[128 * 32];
  const int tid = threadIdx.x;
  const int wave = tid >> 6, lane = tid & 63;
  const int g = lane >> 4, lr = lane & 15;
  const int bid = blockIdx.x;
  const int swz = (bid & 7) * ((int)gridDim.x >> 3) + (bid >> 3);
  const int m0 = (swz / nx) * 128, n0 = (swz % nx) * 128;
  const int wr = (wave >> 1) * 64, wc = (wave & 1) * 64;
  f32x4 acc[4][4] = {};

  for (int k0 = 0; k0 < K; k0 += 32) {
    __syncthreads();
#pragma unroll
    for (int j = 0; j < 2; ++j) {
      const int e = tid * 8 + j * 2048;
      const int r = e >> 5, c = e & 31;
      const u16* ga = A + (size_t)(m0 + r) * K + k0 + c;
      const u16* gb = BT + (size_t)(n0 + r) * K + k0 + c;
      load_lds16(ga, (void*)(As + wave * 512 + j * 2048));
      load_lds16(gb, (void*)(Bs + wave * 512 + j * 2048));
    }
    __syncthreads();
    const u16* pa = As + (wr + lr) * 32 + g * 8;
    const u16* pb = Bs + (wc + lr) * 32 + g * 8;
    bf16x8 a[4], b[4];
#pragma unroll
    for (int i = 0; i < 4; ++i) a[i] = *(const bf16x8*)(pa + i * 16 * 32);
#pragma unroll
    for (int j = 0; j < 4; ++j) b[j] = *(const bf16x8*)(pb + j * 16 * 32);
#pragma unroll
    for (int i = 0; i < 4; ++i)
#pragma unroll
      for (int j = 0; j < 4; ++j)
        acc[i][j] = __builtin_amdgcn_mfma_f32_16x16x32_bf16(a[i], b[j], acc[i][j], 0, 0, 0);
  }

#pragma unroll
  for (int i = 0; i < 4; ++i)
#pragma unroll
    for (int j = 0; j < 4; ++j)
#pragma unroll
      for (int r = 0; r < 4; ++r) {
        int row = m0 + wr + i * 16 + g * 4 + r;
        int col = n0 + wc + j * 16 + lr;
        float v = acc[i][j][r] + bias[col];
        if (BF16_OUT)
          ((u16*)Cv)[(size_t)row * N + col] = f2bf(v);
        else
          ((float*)Cv)[(size_t)row * N + col] = v;
      }
}

// ---------------- causal flash attention: 4 waves/block share staged K/V (R8 body) ----------------
// Units with g < 8 cover their full causal range -> normalized direct write (no combine).
#define MNEG 30000.0f
template <int CH, int DIRECT>
__global__ __launch_bounds__(256, 3) void attn(const u16* __restrict__ qkv, const u16* __restrict__ vT,
                                               u16* __restrict__ pO, float* __restrict__ pml,
                                               u16* __restrict__ aout) {
  __shared__ __align__(16) u16 KV[4][4096];  // K buf0,buf1, V buf0,buf1 (swizzled 64x64)

  const int bid = blockIdx.x;
  const int h = bid % 12;
  int g, c;
  if (DIRECT) {
    g = 31 - bid / 12;
    c = 0;
  } else {
    const int u = 79 - bid / 12;  // heavy chunks first
    if (u < 8) { g = u; c = 0; }
    else if (u < 24) { g = 8 + ((u - 8) >> 1); c = (u - 8) & 1; }
    else if (u < 48) { g = 16 + (u - 24) / 3; c = (u - 24) % 3; }
    else { g = 24 + ((u - 48) >> 2); c = (u - 48) & 3; }
  }

  const int tid = threadIdx.x;
  const int wave = tid >> 6;
  const int l = tid & 63;
  const int lr = l & 31;   // q-row within wave's tile
  const int H = l >> 5;    // lane half
  const int H4 = H * 4, H8 = H * 8;

  const int qt = 4 * g + wave;
  const int q0 = qt * 32;
  const int nkt = (qt >> 1) + 1;              // tiles this wave needs
  const int t0 = DIRECT ? 0 : c * CH;
  const int tend = min(2 * g + 2, t0 + CH);   // block-uniform tile range

  const u16* kgb = qkv + 768 + h * 64;
  const u16* vgb = vT + (size_t)h * 64 * 4096;

  // staging: wave w issue i covers rows 16w+8i..+7; lane -> row 16w+8i+srow, chunk l&7
  const int srow = l >> 3;
  int kSo[2], vSo[2];
#pragma unroll
  for (int i = 0; i < 2; ++i) {
    const int row = 16 * wave + 8 * i + srow;
    const int sc = ((l & 7) ^ srow ^ (2 * wave + i)) << 3;
    kSo[i] = row * 2304 + sc;
    vSo[i] = row * 4096 + sc;
  }

  // hoisted LDS read pointers (K buf0; V = +8192, buf1 = +4096)
  const u16* Rd[2][4];
#pragma unroll
  for (int b2 = 0; b2 < 2; ++b2) {
    const int row = 32 * b2 + lr;
    const int sw = (row ^ (row >> 3)) & 7;
#pragma unroll
    for (int cc = 0; cc < 4; ++cc)
      Rd[b2][cc] = &KV[0][row * 64 + (((2 * cc + H) ^ sw) << 3)];
  }

  // Q B-fragments, prescaled by 0.125*log2(e)
  bf16x8 qB[4];
  {
    const u16* qp = qkv + (size_t)(q0 + lr) * 2304 + h * 64;
    const float qs = 0.125f * 1.4426950408889634f;
#pragma unroll
    for (int cc = 0; cc < 4; ++cc) {
      bf16x8 raw = *(const bf16x8*)(qp + 16 * cc + H8);
#pragma unroll
      for (int e = 0; e < 8; ++e) qB[cc][e] = (__bf16)((float)raw[e] * qs);
    }
  }

  f32x16 O[2] = {};
  float mst = -MNEG, lst = 0.f;

#define STAGE(T, BUF)                                                      \
  {                                                                        \
    const size_t kk = (size_t)(T) * 64;                                    \
    _Pragma("unroll") for (int i = 0; i < 2; ++i) {                        \
      load_lds16(kgb + kk * 2304 + kSo[i], &KV[(BUF)][(2 * wave + i) * 512]); \
      load_lds16(vgb + kk + vSo[i], &KV[2 + (BUF)][(2 * wave + i) * 512]); \
    }                                                                      \
  }

#define BODY(T, BUF)                                                                        \
  {                                                                                         \
    if ((T) + 1 < tend) {                                                                   \
      STAGE((T) + 1, (BUF) ^ 1);                                                            \
      asm volatile("s_waitcnt vmcnt(4)" ::: "memory");                                      \
    } else {                                                                                \
      asm volatile("s_waitcnt vmcnt(0)" ::: "memory");                                      \
    }                                                                                       \
    __builtin_amdgcn_s_barrier();                                                           \
    __builtin_amdgcn_sched_barrier(0);                                                      \
    f32x16 s[2] = {};                                                                       \
    _Pragma("unroll") for (int kb = 0; kb < 2; ++kb)                                        \
      _Pragma("unroll") for (int cc = 0; cc < 4; ++cc) {                                    \
        bf16x8 kf = *(const bf16x8*)(Rd[kb][cc] + (BUF) * 4096);                            \
        s[kb] = __builtin_amdgcn_mfma_f32_32x32x16_bf16(kf, qB[cc], s[kb], 0, 0, 0);        \
      }                                                                                     \
    bf16x8 vf[2][4];                                                                        \
    _Pragma("unroll") for (int da = 0; da < 2; ++da)                                        \
      _Pragma("unroll") for (int cc = 0; cc < 4; ++cc)                                      \
        vf[da][cc] = *(const bf16x8*)(Rd[da][cc] + 8192 + (BUF) * 4096);                    \
    if ((T) >= nkt - 1) {                                                                   \
      const int rel = q0 + lr - (T) * 64;                                                   \
      _Pragma("unroll") for (int kb = 0; kb < 2; ++kb)                                      \
        _Pragma("unroll") for (int r = 0; r < 16; ++r)                                      \
          if (32 * kb + (r & 3) + 8 * (r >> 2) + H4 > rel) s[kb][r] = -MNEG;                \
    }                                                                                       \
    float mx = s[0][0];                                                                     \
    _Pragma("unroll") for (int kb = 0; kb < 2; ++kb)                                        \
      _Pragma("unroll") for (int r = 0; r < 16; ++r) mx = fmaxf(mx, s[kb][r]);              \
    mx = fmaxf(mx, __shfl_xor(mx, 32));                                                     \
    if (__any(mx > mst + 12.f)) {                                                           \
      const float mn = fmaxf(mst, mx);                                                      \
      const float alpha = __builtin_amdgcn_exp2f(mst - mn);                                 \
      mst = mn;                                                                             \
      lst *= alpha;                                                                         \
      O[0] *= alpha;                                                                        \
      O[1] *= alpha;                                                                        \
    }                                                                                       \
    float rs = 0.f;                                                                         \
    _Pragma("unroll") for (int kb = 0; kb < 2; ++kb)                                        \
      _Pragma("unroll") for (int r = 0; r < 16; ++r) {                                      \
        const float p = __builtin_amdgcn_exp2f(s[kb][r] - mst);                             \
        s[kb][r] = p;                                                                       \
        rs += p;                                                                            \
      }                                                                                     \
    rs += __shfl_xor(rs, 32);                                                               \
    lst += rs;                                                                              \
    unsigned w[16];                                                                         \
    _Pragma("unroll") for (int kb = 0; kb < 2; ++kb)                                        \
      _Pragma("unroll") for (int j2 = 0; j2 < 4; ++j2) {                                    \
        asm("v_cvt_pk_bf16_f32 %0, %1, %2"                                                  \
            : "=v"(w[kb * 8 + j2 * 2]) : "v"(s[kb][4 * j2]), "v"(s[kb][4 * j2 + 1]));       \
        asm("v_cvt_pk_bf16_f32 %0, %1, %2"                                                  \
            : "=v"(w[kb * 8 + j2 * 2 + 1]) : "v"(s[kb][4 * j2 + 2]), "v"(s[kb][4 * j2 + 3])); \
      }                                                                                     \
    unsigned recv[8];                                                                       \
    _Pragma("unroll") for (int cc = 0; cc < 4; ++cc)                                        \
      _Pragma("unroll") for (int m = 0; m < 2; ++m) {                                       \
        const unsigned send = H ? w[4 * cc + m] : w[4 * cc + 2 + m];                        \
        recv[cc * 2 + m] = (unsigned)__shfl_xor((int)send, 32);                             \
      }                                                                                     \
    _Pragma("unroll") for (int cc = 0; cc < 4; ++cc) {                                      \
      union { unsigned u[4]; bf16x8 v; } Bp;                                                \
      Bp.u[0] = H ? recv[2 * cc] : w[4 * cc];                                               \
      Bp.u[1] = H ? recv[2 * cc + 1] : w[4 * cc + 1];                                       \
      Bp.u[2] = H ? w[4 * cc + 2] : recv[2 * cc];                                           \
      Bp.u[3] = H ? w[4 * cc + 3] : recv[2 * cc + 1];                                       \
      O[0] = __builtin_amdgcn_mfma_f32_32x32x16_bf16(vf[0][cc], Bp.v, O[0], 0, 0, 0);       \
      O[1] = __builtin_amdgcn_mfma_f32_32x32x16_bf16(vf[1][cc], Bp.v, O[1], 0, 0, 0);       \
    }                                                                                       \
    __builtin_amdgcn_s_barrier();                                                           \
  }

  STAGE(t0, 0);
  int t = t0;
  for (; t + 2 <= tend; t += 2) {
    BODY(t, 0);
    BODY(t + 1, 1);
  }
  if (t < tend) BODY(t, 0);
#undef BODY
#undef STAGE

  if (DIRECT || g < 8) {
    const float inv = 1.0f / lst;
    u16* orow = aout + (size_t)(q0 + lr) * 768 + h * 64;
#pragma unroll
    for (int da = 0; da < 2; ++da)
#pragma unroll
      for (int j2 = 0; j2 < 4; ++j2) {
        ushort4 st;
        st.x = f2bf(O[da][4 * j2 + 0] * inv);
        st.y = f2bf(O[da][4 * j2 + 1] * inv);
        st.z = f2bf(O[da][4 * j2 + 2] * inv);
        st.w = f2bf(O[da][4 * j2 + 3] * inv);
        *(ushort4*)(orow + 32 * da + 8 * j2 + H4) = st;
      }
  } else {
    const int slot = (h * 128 + qt) * 4 + c;
    u16* po = pO + (size_t)slot * 2048 + lr * 64;
#pragma unroll
    for (int da = 0; da < 2; ++da)
#pragma unroll
      for (int j2 = 0; j2 < 4; ++j2) {
        ushort4 st;
        st.x = f2bf(O[da][4 * j2 + 0]);
        st.y = f2bf(O[da][4 * j2 + 1]);
        st.z = f2bf(O[da][4 * j2 + 2]);
        st.w = f2bf(O[da][4 * j2 + 3]);
        *(ushort4*)(po + 32 * da + 8 * j2 + H4) = st;
      }
    if (H == 0) {
      float2 ml; ml.x = mst; ml.y = lst;
      *(float2*)(pml + (size_t)slot * 64 + lr * 2) = ml;
    }
  }
}

// combine partials: one block per (h, qt) with qt >= 32
__global__ __launch_bounds__(64) void combine(const u16* __restrict__ pO, const float* __restrict__ pml,
                                              u16* __restrict__ aout, int ncmax, int CHv) {
  const int bid = blockIdx.x;
  const int h = bid % 12, qt = 32 + bid / 12;
  const int nkt = (qt >> 1) + 1;
  const int nc = (nkt + CHv - 1) / CHv;
  const int sb = (h * 128 + qt) * ncmax;
  const int t = threadIdx.x;
  const int row = t & 31, H = t >> 5;

  float m[4], lw[4];
  float M = -__builtin_inff();
#pragma unroll
  for (int c = 0; c < 4; ++c)
    if (c < nc) {
      m[c] = pml[(size_t)(sb + c) * 64 + row * 2];
      M = fmaxf(M, m[c]);
    }
  float L = 0.f;
#pragma unroll
  for (int c = 0; c < 4; ++c)
    if (c < nc) {
      lw[c] = __builtin_amdgcn_exp2f(m[c] - M);
      L += pml[(size_t)(sb + c) * 64 + row * 2 + 1] * lw[c];
    }

  float acc[32] = {};
#pragma unroll
  for (int c = 0; c < 4; ++c)
    if (c < nc) {
      const u16* p = pO + (size_t)(sb + c) * 2048 + row * 64 + 32 * H;
      const float wgt = lw[c];
#pragma unroll
      for (int k = 0; k < 4; ++k) {
        bf16x8 v = *(const bf16x8*)(p + 8 * k);
#pragma unroll
        for (int e = 0; e < 8; ++e) acc[k * 8 + e] += (float)v[e] * wgt;
      }
    }

  const float inv = 1.0f / L;
  u16 ov[32];
#pragma unroll
  for (int d = 0; d < 32; ++d) ov[d] = f2bf(acc[d] * inv);
  u16* dst = aout + (size_t)(qt * 32 + row) * 768 + h * 64 + 32 * H;
#pragma unroll
  for (int k = 0; k < 4; ++k) *(uint4*)(dst + 8 * k) = *(const uint4*)(ov + 8 * k);
}

// ---------------- launch ----------------
extern "C" void kernel_launch(void* const* d_in, const int* in_sizes, int n_in,
                              void* d_out, int out_size, void* d_ws, size_t ws_size,
                              hipStream_t stream) {
  const float* x = (const float*)d_in[0];
  const float* w_attn = (const float*)d_in[1];
  const float* b_attn = (const float*)d_in[2];
  const float* w_proj = (const float*)d_in[3];
  const float* b_proj = (const float*)d_in[4];
  float* out = (float*)d_out;

  const int S = 4096, D = 768;
  u16* xb = (u16*)d_ws;                 // [4096][768]
  u16* wTa = xb + (size_t)S * D;        // [2304][768]
  u16* wTp = wTa + (size_t)3 * D * D;   // [768][768]
  u16* qkv = wTp + (size_t)D * D;       // [4096][2304]
  u16* abuf = qkv + (size_t)S * 3 * D;  // [4096][768]
  u16* vTb = abuf + (size_t)S * D;      // [12][64][4096]
  u16* pO = vTb + (size_t)12 * 64 * 4096;

  const size_t base_bytes = (size_t)(3145728 + 1769472 + 589824 + 9437184 + 3145728 + 3145728) * 2;
  const size_t need16 = base_bytes + (size_t)6144 * 2048 * 2 + (size_t)6144 * 64 * 4;

  prep<<<dim3(5376), 256, 0, stream>>>(x, w_attn, w_proj, xb, wTa, wTp);
  gemm_bt<1><<<dim3(576), 256, 0, stream>>>(xb, wTa, b_attn, qkv, S, 3 * D, D, 18);
  vtrans<<<dim3(S / 64, 12), 256, 0, stream>>>(qkv, vTb);

  if (ws_size >= need16) {
    float* pml = (float*)(pO + (size_t)6144 * 2048);
    attn<16, 0><<<dim3(12 * 80), 256, 0, stream>>>(qkv, vTb, pO, pml, abuf);
    combine<<<dim3(12 * 96), 64, 0, stream>>>(pO, pml, abuf, 4, 16);
  } else {
    attn<64, 1><<<dim3(12 * 32), 256, 0, stream>>>(qkv, vTb, abuf, (float*)abuf, abuf);
  }

  gemm_bt<0><<<dim3(192), 256, 0, stream>>>(abuf, wTp, b_proj, out, S, D, D, 6);
}